// Round 4
// baseline (267.292 us; speedup 1.0000x reference)
//
#include <hip/hip_runtime.h>

#define N_NODES 2048
#define N_EDGES 32768
#define BT      128           // B*T
#define TT      16
#define CH      32
#define E2      (N_EDGES + N_NODES)

// ---------------- degree + attr segment sum ----------------
__global__ void deg_attr_kernel(const int* __restrict__ ei,
                                const float* __restrict__ ea,
                                int* __restrict__ deg, float* __restrict__ asum) {
    int e = blockIdx.x * 256 + threadIdx.x;
    if (e < N_EDGES) {
        int dst = ei[N_EDGES + e];
        atomicAdd(&deg[dst], 1);
        atomicAdd(&asum[dst], ea[e]);
    }
}

// ---------------- row_ptr scan (single wave) ----------------
__global__ void scan_kernel(const int* __restrict__ deg, int* __restrict__ rowp) {
    int lane = threadIdx.x;          // 64 threads
    int base = lane * 32;
    int loc[32];
    int s = 0;
    #pragma unroll
    for (int i = 0; i < 32; ++i) { loc[i] = s; s += deg[base + i] + 1; } // +1 self loop
    int inc = s;
    #pragma unroll
    for (int d = 1; d < 64; d <<= 1) {
        int v = __shfl_up(inc, d, 64);
        if (lane >= d) inc += v;
    }
    int excl = inc - s;
    #pragma unroll
    for (int i = 0; i < 32; ++i) rowp[base + i] = excl + loc[i];
    if (lane == 63) rowp[N_NODES] = inc;
}

// ---------------- scatter edges into CSR (by dst) ----------------
__global__ void scatter_kernel(const int* __restrict__ ei,
                               const float* __restrict__ ea,
                               const int* __restrict__ deg, const float* __restrict__ asum,
                               const int* __restrict__ rowp, int* __restrict__ fill,
                               int* __restrict__ col, float* __restrict__ attr_s) {
    int e = blockIdx.x * 256 + threadIdx.x;
    if (e >= E2) return;
    int src, dst; float a;
    if (e < N_EDGES) {
        src = ei[e]; dst = ei[N_EDGES + e]; a = ea[e];
    } else {
        int n = e - N_EDGES;
        src = n; dst = n;
        a = asum[n] / fmaxf((float)deg[n], 1.0f);   // mean edge attr
    }
    int pos = atomicAdd(&fill[dst], 1);
    col[rowp[dst] + pos]    = src;
    attr_s[rowp[dst] + pos] = a;
}

// ---------------- projection: one node per block; xl transposed [n][c][bt], xr normal ----------------
__global__ __launch_bounds__(256) void proj_kernel(
        const float* __restrict__ x,
        const float* __restrict__ Wl, const float* __restrict__ bl,
        const float* __restrict__ Wr, const float* __restrict__ br,
        float* __restrict__ xlt, float* __restrict__ xr) {
    __shared__ float xs[128 * 32];     // [bt][f]
    __shared__ float wl[1024], wr[1024];
    int n = blockIdx.x;
    int tid = threadIdx.x;
    for (int i = tid; i < 1024; i += 256) { wl[i] = Wl[i]; wr[i] = Wr[i]; }
    #pragma unroll
    for (int i = 0; i < 16; ++i) {
        int e = i * 256 + tid;
        int bt = e >> 5, f = e & 31;
        xs[e] = x[((long)bt * N_NODES + n) * 32 + f];
    }
    __syncthreads();
    int c = tid & 31;
    int btl = tid >> 5;                // 0..7
    float blc = bl[c], brc = br[c];
    for (int i = 0; i < 16; ++i) {
        int bt = i * 8 + btl;
        float al = 0.f, ar = 0.f;
        #pragma unroll
        for (int f = 0; f < 32; ++f) {
            float xv = xs[bt * 32 + f];           // broadcast read
            al += xv * wl[f * 32 + c];
            ar += xv * wr[f * 32 + c];
        }
        xlt[((long)n * 32 + c) * 128 + bt]   = al + blc;   // transposed
        xr[((long)bt * N_NODES + n) * 32 + c] = ar + brc;  // normal
    }
}

// ---------------- GAT: lane = bt; one wave = (node, 64 bt); no shfl, no max-tracking ----------------
__global__ __launch_bounds__(256) void gat_kernel(
        const float* __restrict__ xlt,   // [n][c][bt]
        const float* __restrict__ xr,    // [bt][n][c]
        const int* __restrict__ rowp, const int* __restrict__ col,
        const float* __restrict__ attr_s,
        const float* __restrict__ We, const float* __restrict__ att,
        const float* __restrict__ ob,
        float* __restrict__ out) {       // [bt][n][c]
    int tid = threadIdx.x;
    int wv = tid >> 6, lane = tid & 63;
    int task = blockIdx.x * 4 + wv;      // 4096 tasks = 2048 n x 2 btg
    int n   = task >> 1;
    int bt  = ((task & 1) << 6) | lane;

    float Wec[32], attc[32];             // uniform -> scalar regs
    #pragma unroll
    for (int c = 0; c < 32; ++c) { Wec[c] = We[c]; attc[c] = att[c]; }

    float xrv[32], accv[32];
    const float* xrp = xr + ((long)bt * N_NODES + n) * CH;
    #pragma unroll
    for (int c = 0; c < 32; ++c) { xrv[c] = xrp[c]; accv[c] = 0.f; }

    int beg = rowp[n];
    int end = rowp[n + 1];
    float den = 0.f;
    const float* xbase = xlt + bt;
    for (int j = beg; j < end; ++j) {
        int   src = col[j];
        float av  = attr_s[j];
        const float* gp = xbase + (long)src * (CH * 128);
        float xlv[32];
        #pragma unroll
        for (int c = 0; c < 32; ++c) xlv[c] = gp[c * 128];
        float p0 = 0.f, p1 = 0.f, p2 = 0.f, p3 = 0.f;
        #pragma unroll
        for (int k = 0; k < 8; ++k) {
            { int c = k;      float m = xlv[c] + fmaf(av, Wec[c], xrv[c]); p0 = fmaf(attc[c], fmaxf(m, 0.2f * m), p0); }
            { int c = k + 8;  float m = xlv[c] + fmaf(av, Wec[c], xrv[c]); p1 = fmaf(attc[c], fmaxf(m, 0.2f * m), p1); }
            { int c = k + 16; float m = xlv[c] + fmaf(av, Wec[c], xrv[c]); p2 = fmaf(attc[c], fmaxf(m, 0.2f * m), p2); }
            { int c = k + 24; float m = xlv[c] + fmaf(av, Wec[c], xrv[c]); p3 = fmaf(attc[c], fmaxf(m, 0.2f * m), p3); }
        }
        // scores are analytically bounded (|p| < ~10); softmax is shift-invariant so no
        // max subtraction needed. Clamp as overflow insurance (no-op for this data).
        float p = fminf((p0 + p1) + (p2 + p3), 80.f);
        float w = __expf(p);
        den += w;
        #pragma unroll
        for (int c = 0; c < 32; ++c) accv[c] = fmaf(w, xlv[c], accv[c]);
    }
    float inv = 1.f / den;
    float* op = out + ((long)bt * N_NODES + n) * CH;
    #pragma unroll
    for (int c = 0; c < 32; ++c) op[c] = fmaf(accv[c], inv, ob[c]);
}

// ---------------- GRU: weights in VGPRs, no LDS; 2 seqs/wave; in-place on d_out ----------------
__global__ __launch_bounds__(256, 2) void gru_kernel(
        const float* __restrict__ wih, const float* __restrict__ whh,
        const float* __restrict__ bih, const float* __restrict__ bhh,
        float* hio) {   // [b,t,n,c]; read h (GAT out) then overwrite with y
    int tid  = threadIdx.x;
    int lane = tid & 63;
    int c    = tid & 31;
    int sbase = lane & 32;
    int seq  = blockIdx.x * 8 + (tid >> 5);  // 8 sequences per block, seq = b*2048 + n
    int b = seq >> 11;
    int n = seq & 2047;

    // per-lane weight rows (c, 32+c, 64+c) of w_ih and w_hh -> registers
    float wi0[32], wi1[32], wi2[32], wh0[32], wh1[32], wh2[32];
    #pragma unroll
    for (int f4 = 0; f4 < 8; ++f4) {
        float4 a;
        a = *(const float4*)&wih[( 0 + c) * 32 + f4 * 4]; wi0[f4*4]=a.x; wi0[f4*4+1]=a.y; wi0[f4*4+2]=a.z; wi0[f4*4+3]=a.w;
        a = *(const float4*)&wih[(32 + c) * 32 + f4 * 4]; wi1[f4*4]=a.x; wi1[f4*4+1]=a.y; wi1[f4*4+2]=a.z; wi1[f4*4+3]=a.w;
        a = *(const float4*)&wih[(64 + c) * 32 + f4 * 4]; wi2[f4*4]=a.x; wi2[f4*4+1]=a.y; wi2[f4*4+2]=a.z; wi2[f4*4+3]=a.w;
        a = *(const float4*)&whh[( 0 + c) * 32 + f4 * 4]; wh0[f4*4]=a.x; wh0[f4*4+1]=a.y; wh0[f4*4+2]=a.z; wh0[f4*4+3]=a.w;
        a = *(const float4*)&whh[(32 + c) * 32 + f4 * 4]; wh1[f4*4]=a.x; wh1[f4*4+1]=a.y; wh1[f4*4+2]=a.z; wh1[f4*4+3]=a.w;
        a = *(const float4*)&whh[(64 + c) * 32 + f4 * 4]; wh2[f4*4]=a.x; wh2[f4*4+1]=a.y; wh2[f4*4+2]=a.z; wh2[f4*4+3]=a.w;
    }
    float bi0 = bih[c], bi1 = bih[32 + c], bi2 = bih[64 + c];
    float bh0 = bhh[c], bh1 = bhh[32 + c], bh2 = bhh[64 + c];

    const long STR = (long)N_NODES * CH;     // per-t stride
    long base = ((long)b * TT) * STR + (long)n * CH + c;

    float hc = 0.f;
    float xv = hio[base];                    // prefetch t=0
    #pragma unroll 1
    for (int t = 0; t < TT; ++t) {
        float xnext = (t + 1 < TT) ? hio[base + (long)(t + 1) * STR] : 0.f;
        float gx0 = bi0, gx1 = bi1, gx2 = bi2;
        float gh0 = bh0, gh1 = bh1, gh2 = bh2;
        #pragma unroll
        for (int f = 0; f < 32; ++f) {
            float xf = __shfl(xv, sbase | f, 64);
            float hf = __shfl(hc, sbase | f, 64);
            gx0 = fmaf(xf, wi0[f], gx0);
            gx1 = fmaf(xf, wi1[f], gx1);
            gx2 = fmaf(xf, wi2[f], gx2);
            gh0 = fmaf(hf, wh0[f], gh0);
            gh1 = fmaf(hf, wh1[f], gh1);
            gh2 = fmaf(hf, wh2[f], gh2);
        }
        float r  = 1.f / (1.f + __expf(-(gx0 + gh0)));
        float z  = 1.f / (1.f + __expf(-(gx1 + gh1)));
        float a  = gx2 + r * gh2;
        float e2 = __expf(2.f * a);
        float nc = 1.f - 2.f / (e2 + 1.f);             // tanh, no inf/inf
        hc = (1.f - z) * nc + z * hc;
        hio[base + (long)t * STR] = hc;                // overwrite same element
        xv = xnext;
    }
}

extern "C" void kernel_launch(void* const* d_in, const int* in_sizes, int n_in,
                              void* d_out, int out_size, void* d_ws, size_t ws_size,
                              hipStream_t stream) {
    const float* x    = (const float*)d_in[0];
    const int*   ei   = (const int*)d_in[1];
    const float* ea   = (const float*)d_in[2];
    const float* Wl   = (const float*)d_in[3];
    const float* bl   = (const float*)d_in[4];
    const float* Wr   = (const float*)d_in[5];
    const float* br   = (const float*)d_in[6];
    const float* We   = (const float*)d_in[7];
    const float* att  = (const float*)d_in[8];
    const float* ob   = (const float*)d_in[9];
    const float* wih  = (const float*)d_in[10];
    const float* whh  = (const float*)d_in[11];
    const float* bih  = (const float*)d_in[12];
    const float* bhh  = (const float*)d_in[13];
    float* out = (float*)d_out;

    // ---- workspace carve: small CSR metadata FIRST, then big arrays ----
    const long RB = (long)BT * N_NODES * CH;   // 8,388,608 elements
    int*   deg  = (int*)d_ws;                  // N
    float* asum = (float*)(deg + N_NODES);     // N
    int*   fill = (int*)(asum + N_NODES);      // N
    int*   rowp = fill + N_NODES;              // N+1 (padded to +16)
    int*   col  = rowp + (N_NODES + 16);       // E2
    float* attr_s = (float*)(col + E2);        // E2
    float* xlt  = (float*)(attr_s + E2);
    xlt = (float*)(((uintptr_t)xlt + 255) & ~(uintptr_t)255);
    float* xr   = xlt + RB;

    // zero the three counter arrays (contiguous: deg, asum, fill)
    hipMemsetAsync(deg, 0, 3 * N_NODES * sizeof(int), stream);

    deg_attr_kernel<<<N_EDGES / 256, 256, 0, stream>>>(ei, ea, deg, asum);
    scan_kernel<<<1, 64, 0, stream>>>(deg, rowp);
    scatter_kernel<<<(E2 + 255) / 256, 256, 0, stream>>>(ei, ea, deg, asum, rowp, fill, col, attr_s);
    proj_kernel<<<N_NODES, 256, 0, stream>>>(x, Wl, bl, Wr, br, xlt, xr);
    gat_kernel<<<(N_NODES * 2) / 4, 256, 0, stream>>>(xlt, xr, rowp, col, attr_s, We, att, ob, out);
    gru_kernel<<<(BT / TT * N_NODES) / 8, 256, 0, stream>>>(wih, whh, bih, bhh, out);
}